// Round 3
// baseline (283.651 us; speedup 1.0000x reference)
//
#include <hip/hip_runtime.h>

// YOLOv1 loss, MI355X. Memory-bound streaming reduction, single fused kernel.
// y_pred: (16384,7,7,30) f32, y_true: (16384,7,7,6) f32, out: scalar f32.
// Staging via global_load_lds (width=16), last-block finalize via agent-scope
// release/acquire atomic counter (correct across non-coherent XCD L2s).

#define CELLS  (16384 * 49)      // 802816 cells
#define TILE   256               // cells per tile (= block threads)
#define NTILES (CELLS / TILE)    // 3136, exact
#define NCH    30
#define NTR    6
#define LCOORD 5.0f
#define LNOOBJ 0.5f
#define PART_OFF 16              // float index in ws where per-block partials begin

__device__ __forceinline__ float iou_one(float x, float y, float w, float h,
                                         float t0, float t1, float t2, float t3) {
    float b1x1 = x - w * 0.5f, b1x2 = x + w * 0.5f;
    float b1y1 = y - h * 0.5f, b1y2 = y + h * 0.5f;
    float b2x1 = t0 - t2 * 0.5f, b2x2 = t0 + t2 * 0.5f;
    float b2y1 = t1 - t3 * 0.5f, b2y2 = t1 + t3 * 0.5f;
    float iw = fmaxf(fminf(b1x2, b2x2) - fmaxf(b1x1, b2x1), 0.0f);
    float ih = fmaxf(fminf(b1y2, b2y2) - fmaxf(b1y1, b2y1), 0.0f);
    float inter = iw * ih;
    float uni = w * h + t2 * t3 - inter;
    return inter / (uni + 1e-6f);
}

__global__ __launch_bounds__(256) void yolo_fused(const float* __restrict__ yp,
                                                  const float* __restrict__ yt,
                                                  float* __restrict__ ws,
                                                  float* __restrict__ out,
                                                  int nblocks) {
    __shared__ float sp[TILE * NCH];   // 30 KiB
    __shared__ float st[TILE * NTR];   // 6 KiB
    __shared__ float red[4][8];
    __shared__ int is_last;

    const int tid  = threadIdx.x;
    const int wave = tid >> 6, lane = tid & 63;
    float v[6] = {0.f, 0.f, 0.f, 0.f, 0.f, 0.f};

    for (int tile = blockIdx.x; tile < NTILES; tile += gridDim.x) {
        // ---- stage tile via async global->LDS, lane-linear layout ----
        const float4* gp4 = (const float4*)(yp + (size_t)tile * TILE * NCH);
        const float4* gt4 = (const float4*)(yt + (size_t)tile * TILE * NTR);
        float4* sp4 = (float4*)sp;
        float4* st4 = (float4*)st;
        // yp tile: 1920 float4s; chunks of 256 (chunk 7 = 128 -> waves 0,1 only)
        #pragma unroll
        for (int k = 0; k < 8; ++k) {
            int i = k * 256 + tid;
            if (i < TILE * NCH / 4) {
                int base = k * 256 + wave * 64;   // wave-uniform
                __builtin_amdgcn_global_load_lds(
                    (const __attribute__((address_space(1))) void*)(gp4 + i),
                    (__attribute__((address_space(3))) void*)(sp4 + base), 16, 0, 0);
            }
        }
        // yt tile: 384 float4s (chunk 1 = 128 -> waves 0,1 only)
        #pragma unroll
        for (int k = 0; k < 2; ++k) {
            int i = k * 256 + tid;
            if (i < TILE * NTR / 4) {
                int base = k * 256 + wave * 64;
                __builtin_amdgcn_global_load_lds(
                    (const __attribute__((address_space(1))) void*)(gt4 + i),
                    (__attribute__((address_space(3))) void*)(st4 + base), 16, 0, 0);
            }
        }
        __syncthreads();   // drains vmcnt before LDS reads

        // ---- per-cell compute ----
        const float* p = sp + tid * NCH;
        const float* t = st + tid * NTR;
        float t0 = t[0], t1 = t[1], t2 = t[2], t3 = t[3], t4 = t[4];
        int lbl = (int)t[5];

        float iou0 = iou_one(p[0], p[1], p[2], p[3], t0, t1, t2, t3);
        float iou1 = iou_one(p[5], p[6], p[7], p[8], t0, t1, t2, t3);
        // jnp.argmax picks FIRST max on ties -> box1 wins only if strictly greater
        int base = (iou1 > iou0) ? 5 : 0;
        float tb0 = p[base + 0], tb1 = p[base + 1], tb2 = p[base + 2];
        float tb3 = p[base + 3], tb4 = p[base + 4];

        float obj = (t4 != 0.0f) ? 1.0f : 0.0f;
        float noobj = 1.0f - obj;

        float dx = tb0 - t0, dy = tb1 - t1;
        float a0 = obj * (dx * dx + dy * dy);

        float s2 = sqrtf(t2);                 // reference uses y_true[...,2] for BOTH size terms
        float d2 = sqrtf(tb2) - s2;
        float d3 = sqrtf(tb3) - s2;
        float a1 = obj * (d2 * d2 + d3 * d3);

        float pc = fminf(fmaxf(tb4, 1e-7f), 1.0f - 1e-7f);
        float bce = -(t4 * logf(pc) + (1.0f - t4) * log1pf(-pc));
        float a2 = obj * bce;
        float a3 = noobj * bce;

        // log-softmax over 20 logits
        float m = p[10];
        #pragma unroll
        for (int k = 11; k < 30; ++k) m = fmaxf(m, p[k]);
        float se = 0.0f;
        #pragma unroll
        for (int k = 10; k < 30; ++k) se += expf(p[k] - m);
        float nll = logf(se) + m - p[10 + lbl];
        float a4 = obj * nll;

        v[0] += a0; v[1] += a1; v[2] += a2; v[3] += a3; v[4] += a4; v[5] += obj;
        __syncthreads();   // protect LDS before next tile's staging
    }

    // ---- block reduce ----
    #pragma unroll
    for (int j = 0; j < 6; ++j) {
        #pragma unroll
        for (int off = 32; off > 0; off >>= 1)
            v[j] += __shfl_down(v[j], off, 64);
    }
    if (lane == 0) {
        #pragma unroll
        for (int j = 0; j < 6; ++j) red[wave][j] = v[j];
    }
    __syncthreads();
    if (tid == 0) {
        float* dst = ws + PART_OFF + (size_t)blockIdx.x * 8;
        #pragma unroll
        for (int j = 0; j < 6; ++j)
            dst[j] = red[0][j] + red[1][j] + red[2][j] + red[3][j];
        // release: partial stores above become visible before the count bump
        unsigned old = __hip_atomic_fetch_add((unsigned*)ws, 1u,
                                              __ATOMIC_ACQ_REL, __HIP_MEMORY_SCOPE_AGENT);
        is_last = (old == (unsigned)(nblocks - 1)) ? 1 : 0;
    }
    __syncthreads();

    // ---- last block finalizes ----
    if (is_last) {
        float f[6] = {0.f, 0.f, 0.f, 0.f, 0.f, 0.f};
        for (int i = tid; i < nblocks; i += 256) {
            const float* src = ws + PART_OFF + (size_t)i * 8;
            #pragma unroll
            for (int j = 0; j < 6; ++j) f[j] += src[j];
        }
        #pragma unroll
        for (int j = 0; j < 6; ++j) {
            #pragma unroll
            for (int off = 32; off > 0; off >>= 1)
                f[j] += __shfl_down(f[j], off, 64);
        }
        if (lane == 0) {
            #pragma unroll
            for (int j = 0; j < 6; ++j) red[wave][j] = f[j];
        }
        __syncthreads();
        if (tid == 0) {
            float a[6];
            #pragma unroll
            for (int j = 0; j < 6; ++j)
                a[j] = red[0][j] + red[1][j] + red[2][j] + red[3][j];
            float n_obj = a[5];
            float n_noobj = (float)CELLS - n_obj;
            out[0] = (LCOORD * (a[0] + a[1]) + a[2] + a[4]) / n_obj
                   + LNOOBJ * a[3] / n_noobj;
        }
    }
}

extern "C" void kernel_launch(void* const* d_in, const int* in_sizes, int n_in,
                              void* d_out, int out_size, void* d_ws, size_t ws_size,
                              hipStream_t stream) {
    const float* yp = (const float*)d_in[0];  // (16384,7,7,30)
    const float* yt = (const float*)d_in[1];  // (16384,7,7,6)
    float* out = (float*)d_out;
    float* ws = (float*)d_ws;

    int nblocks = NTILES;
    size_t need = 64 + (size_t)nblocks * 8 * sizeof(float);
    if (ws_size < need) {
        nblocks = (int)((ws_size - 64) / (8 * sizeof(float)));
        if (nblocks > NTILES) nblocks = NTILES;
        if (nblocks < 1) nblocks = 1;
    }

    // zero the finish counter (graph-capturable async memset)
    hipMemsetAsync(ws, 0, 64, stream);
    yolo_fused<<<nblocks, 256, 0, stream>>>(yp, yt, ws, out, nblocks);
}

// Round 5
// 237.939 us; speedup vs baseline: 1.1921x; 1.1921x over previous
//
#include <hip/hip_runtime.h>

// YOLOv1 loss, MI355X. Memory-bound streaming reduction.
// y_pred: (16384,7,7,30) f32, y_true: (16384,7,7,6) f32, out: scalar f32.
// Structure: 784 blocks x 4 tiles, reg-staged float4 -> LDS with 1-deep
// register prefetch pipeline (load tile k+1 while computing tile k).
// No device-scope atomics (round-3 lesson: agent acq-rel per block caused
// an L2 writeback/invalidate storm, 3x regression). Separate final kernel.

#define CELLS   (16384 * 49)     // 802816 cells
#define TILE    256              // cells per tile (= block threads)
#define NTILES  (CELLS / TILE)   // 3136, exact
#define NBLOCKS 784              // co-resident grid (<=4 blocks/CU on 256 CUs)
#define TPB     4                // tiles per block: 784*4 = 3136
#define NCH     30
#define NTR     6
#define LCOORD  5.0f
#define LNOOBJ  0.5f

__device__ __forceinline__ float iou_one(float x, float y, float w, float h,
                                         float t0, float t1, float t2, float t3) {
    float b1x1 = x - w * 0.5f, b1x2 = x + w * 0.5f;
    float b1y1 = y - h * 0.5f, b1y2 = y + h * 0.5f;
    float b2x1 = t0 - t2 * 0.5f, b2x2 = t0 + t2 * 0.5f;
    float b2y1 = t1 - t3 * 0.5f, b2y2 = t1 + t3 * 0.5f;
    float iw = fmaxf(fminf(b1x2, b2x2) - fmaxf(b1x1, b2x1), 0.0f);
    float ih = fmaxf(fminf(b1y2, b2y2) - fmaxf(b1y1, b2y1), 0.0f);
    float inter = iw * ih;
    float uni = w * h + t2 * t3 - inter;
    return inter / (uni + 1e-6f);
}

__global__ __launch_bounds__(256) void yolo_main(const float* __restrict__ yp,
                                                 const float* __restrict__ yt,
                                                 float* __restrict__ ws) {
    __shared__ float sp[TILE * NCH];   // 30 KiB
    __shared__ float st[TILE * NTR];   // 6 KiB
    __shared__ float red[4][8];

    const int tid  = threadIdx.x;
    const int wave = tid >> 6, lane = tid & 63;
    const bool lo  = (tid < 128);
    float v[6] = {0.f, 0.f, 0.f, 0.f, 0.f, 0.f};

    float4* sp4 = (float4*)sp;
    float4* st4 = (float4*)st;

    // staging registers: yp tile = 1920 float4 (slots 0..6 full, slot 7 half),
    // yt tile = 384 float4 (slot 0 full, slot 1 half)
    float4 pa[8], pb[2];   // current tile
    float4 qa[8], qb[2];   // next tile (prefetch)

    // ---- prologue: load tile 0 for this block ----
    {
        const int tile = blockIdx.x;
        const float4* gp4 = (const float4*)(yp + (size_t)tile * TILE * NCH);
        const float4* gt4 = (const float4*)(yt + (size_t)tile * TILE * NTR);
        #pragma unroll
        for (int s = 0; s < 7; ++s) pa[s] = gp4[s * 256 + tid];
        if (lo) pa[7] = gp4[7 * 256 + tid];
        pb[0] = gt4[tid];
        if (lo) pb[1] = gt4[256 + tid];
    }

    #pragma unroll
    for (int k = 0; k < TPB; ++k) {
        // ---- write current tile to LDS (coalesced, lane-linear) ----
        #pragma unroll
        for (int s = 0; s < 7; ++s) sp4[s * 256 + tid] = pa[s];
        if (lo) sp4[7 * 256 + tid] = pa[7];
        st4[tid] = pb[0];
        if (lo) st4[256 + tid] = pb[1];
        __syncthreads();

        // ---- issue next tile's global loads (hide HBM latency under compute) ----
        if (k < TPB - 1) {
            const int ntile = blockIdx.x + (k + 1) * NBLOCKS;
            const float4* gp4 = (const float4*)(yp + (size_t)ntile * TILE * NCH);
            const float4* gt4 = (const float4*)(yt + (size_t)ntile * TILE * NTR);
            #pragma unroll
            for (int s = 0; s < 7; ++s) qa[s] = gp4[s * 256 + tid];
            if (lo) qa[7] = gp4[7 * 256 + tid];
            qb[0] = gt4[tid];
            if (lo) qb[1] = gt4[256 + tid];
        }

        // ---- per-cell compute (identical expression order to round 1, absmax 0) ----
        {
            const float* p = sp + tid * NCH;
            const float* t = st + tid * NTR;
            float t0 = t[0], t1 = t[1], t2 = t[2], t3 = t[3], t4 = t[4];
            int lbl = (int)t[5];

            float iou0 = iou_one(p[0], p[1], p[2], p[3], t0, t1, t2, t3);
            float iou1 = iou_one(p[5], p[6], p[7], p[8], t0, t1, t2, t3);
            // jnp.argmax picks FIRST max on ties -> box1 wins only if strictly greater
            int base = (iou1 > iou0) ? 5 : 0;
            float tb0 = p[base + 0], tb1 = p[base + 1], tb2 = p[base + 2];
            float tb3 = p[base + 3], tb4 = p[base + 4];

            float obj = (t4 != 0.0f) ? 1.0f : 0.0f;
            float noobj = 1.0f - obj;

            float dx = tb0 - t0, dy = tb1 - t1;
            float a0 = obj * (dx * dx + dy * dy);

            float s2 = sqrtf(t2);              // reference uses y_true[...,2] for BOTH size terms
            float d2 = sqrtf(tb2) - s2;
            float d3 = sqrtf(tb3) - s2;
            float a1 = obj * (d2 * d2 + d3 * d3);

            float pc = fminf(fmaxf(tb4, 1e-7f), 1.0f - 1e-7f);
            float bce = -(t4 * logf(pc) + (1.0f - t4) * log1pf(-pc));
            float a2 = obj * bce;
            float a3 = noobj * bce;

            float m = p[10];
            #pragma unroll
            for (int c = 11; c < 30; ++c) m = fmaxf(m, p[c]);
            float se = 0.0f;
            #pragma unroll
            for (int c = 10; c < 30; ++c) se += expf(p[c] - m);
            float nll = logf(se) + m - p[10 + lbl];
            float a4 = obj * nll;

            v[0] += a0; v[1] += a1; v[2] += a2; v[3] += a3; v[4] += a4; v[5] += obj;
        }
        __syncthreads();   // protect LDS before next tile's ds_write

        // rotate prefetch -> current (full unroll => pure register renaming)
        #pragma unroll
        for (int s = 0; s < 8; ++s) pa[s] = qa[s];
        pb[0] = qb[0]; pb[1] = qb[1];
    }

    // ---- block reduce ----
    #pragma unroll
    for (int j = 0; j < 6; ++j) {
        #pragma unroll
        for (int off = 32; off > 0; off >>= 1)
            v[j] += __shfl_down(v[j], off, 64);
    }
    if (lane == 0) {
        #pragma unroll
        for (int j = 0; j < 6; ++j) red[wave][j] = v[j];
    }
    __syncthreads();
    if (tid == 0) {
        float* dst = ws + (size_t)blockIdx.x * 8;
        #pragma unroll
        for (int j = 0; j < 6; ++j)
            dst[j] = red[0][j] + red[1][j] + red[2][j] + red[3][j];
    }
}

__global__ __launch_bounds__(256) void yolo_final(const float* __restrict__ ws,
                                                  float* __restrict__ out) {
    __shared__ float red[4][8];
    const int tid = threadIdx.x;
    float v[6] = {0.f, 0.f, 0.f, 0.f, 0.f, 0.f};
    for (int i = tid; i < NBLOCKS; i += 256) {
        const float* src = ws + (size_t)i * 8;
        #pragma unroll
        for (int j = 0; j < 6; ++j) v[j] += src[j];
    }
    #pragma unroll
    for (int j = 0; j < 6; ++j) {
        #pragma unroll
        for (int off = 32; off > 0; off >>= 1)
            v[j] += __shfl_down(v[j], off, 64);
    }
    const int wave = tid >> 6, lane = tid & 63;
    if (lane == 0) {
        #pragma unroll
        for (int j = 0; j < 6; ++j) red[wave][j] = v[j];
    }
    __syncthreads();
    if (tid == 0) {
        float a[6];
        #pragma unroll
        for (int j = 0; j < 6; ++j)
            a[j] = red[0][j] + red[1][j] + red[2][j] + red[3][j];
        float n_obj = a[5];
        float n_noobj = (float)CELLS - n_obj;
        out[0] = (LCOORD * (a[0] + a[1]) + a[2] + a[4]) / n_obj
               + LNOOBJ * a[3] / n_noobj;
    }
}

extern "C" void kernel_launch(void* const* d_in, const int* in_sizes, int n_in,
                              void* d_out, int out_size, void* d_ws, size_t ws_size,
                              hipStream_t stream) {
    const float* yp = (const float*)d_in[0];  // (16384,7,7,30)
    const float* yt = (const float*)d_in[1];  // (16384,7,7,6)
    float* out = (float*)d_out;
    float* ws = (float*)d_ws;   // needs 784*8*4 = 25088 B; ws is ~MBs

    yolo_main<<<NBLOCKS, 256, 0, stream>>>(yp, yt, ws);
    yolo_final<<<1, 256, 0, stream>>>(ws, out);
}

// Round 6
// 237.761 us; speedup vs baseline: 1.1930x; 1.0007x over previous
//
#include <hip/hip_runtime.h>

// YOLOv1 loss, MI355X. Memory-bound streaming reduction.
// y_pred: (16384,7,7,30) f32, y_true: (16384,7,7,6) f32, out: scalar f32.
// Structure: 784 blocks x 4 tiles, reg-staged float4 -> LDS with 1-deep
// register prefetch pipeline (load tile k+1 while computing tile k).
// Round-5 lesson: __launch_bounds__(256) alone let the compiler cap VGPRs at
// 64 and spill the 20-float4 prefetch pipeline to scratch (+235 MB HBM writes,
// 128 us). __launch_bounds__(256,4) raises the cap to 128 VGPR — same
// occupancy (LDS already caps at 4 blocks/CU), no spill.
// No device-scope atomics (round-3 lesson: per-block agent acq-rel caused an
// L2 writeback/invalidate storm, 3x regression). Separate final kernel.

#define CELLS   (16384 * 49)     // 802816 cells
#define TILE    256              // cells per tile (= block threads)
#define NTILES  (CELLS / TILE)   // 3136, exact
#define NBLOCKS 784              // co-resident grid (4 blocks/CU on 196 CUs used)
#define TPB     4                // tiles per block: 784*4 = 3136
#define NCH     30
#define NTR     6
#define LCOORD  5.0f
#define LNOOBJ  0.5f

__device__ __forceinline__ float iou_one(float x, float y, float w, float h,
                                         float t0, float t1, float t2, float t3) {
    float b1x1 = x - w * 0.5f, b1x2 = x + w * 0.5f;
    float b1y1 = y - h * 0.5f, b1y2 = y + h * 0.5f;
    float b2x1 = t0 - t2 * 0.5f, b2x2 = t0 + t2 * 0.5f;
    float b2y1 = t1 - t3 * 0.5f, b2y2 = t1 + t3 * 0.5f;
    float iw = fmaxf(fminf(b1x2, b2x2) - fmaxf(b1x1, b2x1), 0.0f);
    float ih = fmaxf(fminf(b1y2, b2y2) - fmaxf(b1y1, b2y1), 0.0f);
    float inter = iw * ih;
    float uni = w * h + t2 * t3 - inter;
    return inter / (uni + 1e-6f);
}

__global__ __launch_bounds__(256, 4) void yolo_main(const float* __restrict__ yp,
                                                    const float* __restrict__ yt,
                                                    float* __restrict__ ws) {
    __shared__ float sp[TILE * NCH];   // 30 KiB
    __shared__ float st[TILE * NTR];   // 6 KiB
    __shared__ float red[4][8];

    const int tid  = threadIdx.x;
    const int wave = tid >> 6, lane = tid & 63;
    const bool lo  = (tid < 128);
    float v[6] = {0.f, 0.f, 0.f, 0.f, 0.f, 0.f};

    float4* sp4 = (float4*)sp;
    float4* st4 = (float4*)st;

    // staging registers: yp tile = 1920 float4 (slots 0..6 full, slot 7 half),
    // yt tile = 384 float4 (slot 0 full, slot 1 half)
    float4 pa[8], pb[2];   // current tile
    float4 qa[8], qb[2];   // next tile (prefetch)

    // ---- prologue: load tile 0 for this block ----
    {
        const int tile = blockIdx.x;
        const float4* gp4 = (const float4*)(yp + (size_t)tile * TILE * NCH);
        const float4* gt4 = (const float4*)(yt + (size_t)tile * TILE * NTR);
        #pragma unroll
        for (int s = 0; s < 7; ++s) pa[s] = gp4[s * 256 + tid];
        if (lo) pa[7] = gp4[7 * 256 + tid];
        pb[0] = gt4[tid];
        if (lo) pb[1] = gt4[256 + tid];
    }

    #pragma unroll
    for (int k = 0; k < TPB; ++k) {
        // ---- write current tile to LDS (coalesced, lane-linear) ----
        #pragma unroll
        for (int s = 0; s < 7; ++s) sp4[s * 256 + tid] = pa[s];
        if (lo) sp4[7 * 256 + tid] = pa[7];
        st4[tid] = pb[0];
        if (lo) st4[256 + tid] = pb[1];
        __syncthreads();

        // ---- issue next tile's global loads (hide HBM latency under compute) ----
        if (k < TPB - 1) {
            const int ntile = blockIdx.x + (k + 1) * NBLOCKS;
            const float4* gp4 = (const float4*)(yp + (size_t)ntile * TILE * NCH);
            const float4* gt4 = (const float4*)(yt + (size_t)ntile * TILE * NTR);
            #pragma unroll
            for (int s = 0; s < 7; ++s) qa[s] = gp4[s * 256 + tid];
            if (lo) qa[7] = gp4[7 * 256 + tid];
            qb[0] = gt4[tid];
            if (lo) qb[1] = gt4[256 + tid];
        }

        // ---- per-cell compute (identical expression order since round 1, absmax 0) ----
        {
            const float* p = sp + tid * NCH;
            const float* t = st + tid * NTR;
            float t0 = t[0], t1 = t[1], t2 = t[2], t3 = t[3], t4 = t[4];
            int lbl = (int)t[5];

            float iou0 = iou_one(p[0], p[1], p[2], p[3], t0, t1, t2, t3);
            float iou1 = iou_one(p[5], p[6], p[7], p[8], t0, t1, t2, t3);
            // jnp.argmax picks FIRST max on ties -> box1 wins only if strictly greater
            int base = (iou1 > iou0) ? 5 : 0;
            float tb0 = p[base + 0], tb1 = p[base + 1], tb2 = p[base + 2];
            float tb3 = p[base + 3], tb4 = p[base + 4];

            float obj = (t4 != 0.0f) ? 1.0f : 0.0f;
            float noobj = 1.0f - obj;

            float dx = tb0 - t0, dy = tb1 - t1;
            float a0 = obj * (dx * dx + dy * dy);

            float s2 = sqrtf(t2);              // reference uses y_true[...,2] for BOTH size terms
            float d2 = sqrtf(tb2) - s2;
            float d3 = sqrtf(tb3) - s2;
            float a1 = obj * (d2 * d2 + d3 * d3);

            float pc = fminf(fmaxf(tb4, 1e-7f), 1.0f - 1e-7f);
            float bce = -(t4 * logf(pc) + (1.0f - t4) * log1pf(-pc));
            float a2 = obj * bce;
            float a3 = noobj * bce;

            float m = p[10];
            #pragma unroll
            for (int c = 11; c < 30; ++c) m = fmaxf(m, p[c]);
            float se = 0.0f;
            #pragma unroll
            for (int c = 10; c < 30; ++c) se += expf(p[c] - m);
            float nll = logf(se) + m - p[10 + lbl];
            float a4 = obj * nll;

            v[0] += a0; v[1] += a1; v[2] += a2; v[3] += a3; v[4] += a4; v[5] += obj;
        }
        __syncthreads();   // protect LDS before next tile's ds_write

        // rotate prefetch -> current (full unroll => pure register renaming)
        #pragma unroll
        for (int s = 0; s < 8; ++s) pa[s] = qa[s];
        pb[0] = qb[0]; pb[1] = qb[1];
    }

    // ---- block reduce ----
    #pragma unroll
    for (int j = 0; j < 6; ++j) {
        #pragma unroll
        for (int off = 32; off > 0; off >>= 1)
            v[j] += __shfl_down(v[j], off, 64);
    }
    if (lane == 0) {
        #pragma unroll
        for (int j = 0; j < 6; ++j) red[wave][j] = v[j];
    }
    __syncthreads();
    if (tid == 0) {
        float* dst = ws + (size_t)blockIdx.x * 8;
        #pragma unroll
        for (int j = 0; j < 6; ++j)
            dst[j] = red[0][j] + red[1][j] + red[2][j] + red[3][j];
    }
}

__global__ __launch_bounds__(256) void yolo_final(const float* __restrict__ ws,
                                                  float* __restrict__ out) {
    __shared__ float red[4][8];
    const int tid = threadIdx.x;
    float v[6] = {0.f, 0.f, 0.f, 0.f, 0.f, 0.f};
    for (int i = tid; i < NBLOCKS; i += 256) {
        const float* src = ws + (size_t)i * 8;
        #pragma unroll
        for (int j = 0; j < 6; ++j) v[j] += src[j];
    }
    #pragma unroll
    for (int j = 0; j < 6; ++j) {
        #pragma unroll
        for (int off = 32; off > 0; off >>= 1)
            v[j] += __shfl_down(v[j], off, 64);
    }
    const int wave = tid >> 6, lane = tid & 63;
    if (lane == 0) {
        #pragma unroll
        for (int j = 0; j < 6; ++j) red[wave][j] = v[j];
    }
    __syncthreads();
    if (tid == 0) {
        float a[6];
        #pragma unroll
        for (int j = 0; j < 6; ++j)
            a[j] = red[0][j] + red[1][j] + red[2][j] + red[3][j];
        float n_obj = a[5];
        float n_noobj = (float)CELLS - n_obj;
        out[0] = (LCOORD * (a[0] + a[1]) + a[2] + a[4]) / n_obj
               + LNOOBJ * a[3] / n_noobj;
    }
}

extern "C" void kernel_launch(void* const* d_in, const int* in_sizes, int n_in,
                              void* d_out, int out_size, void* d_ws, size_t ws_size,
                              hipStream_t stream) {
    const float* yp = (const float*)d_in[0];  // (16384,7,7,30)
    const float* yt = (const float*)d_in[1];  // (16384,7,7,6)
    float* out = (float*)d_out;
    float* ws = (float*)d_ws;   // needs 784*8*4 = 25088 B

    yolo_main<<<NBLOCKS, 256, 0, stream>>>(yp, yt, ws);
    yolo_final<<<1, 256, 0, stream>>>(ws, out);
}

// Round 7
// 159.784 us; speedup vs baseline: 1.7752x; 1.4880x over previous
//
#include <hip/hip_runtime.h>

// YOLOv1 loss, MI355X. Memory-bound streaming reduction.
// y_pred: (16384,7,7,30) f32, y_true: (16384,7,7,6) f32, out: scalar f32.
//
// Round-6 lesson: launch_bounds(256,4) did NOT raise the VGPR allocation
// (still 64 + 235 MB scratch spill). Instead of fighting the register
// allocator, this version needs ZERO staging VGPRs: double-buffered LDS
// filled by global_load_lds (async DMA), counted s_waitcnt vmcnt(9) and raw
// s_barrier (NOT __syncthreads, which drains vmcnt(0) and would serialize
// the prefetch). 128-cell tiles = 1152 float4 = exactly 9 loads/thread
// (uniform per-wave vmcnt counts; LDS dest buf+j is lane-linear as the
// instruction requires). 4 blocks/CU, loads for tile k+2 in flight while
// computing tile k -> HBM pipe stays busy through compute phases.
// No device-scope atomics (round-3 lesson). Separate tiny final kernel.

#define CELLS   (16384 * 49)       // 802816 cells
#define TILE    128                // cells per tile (= block threads)
#define NTILES  (CELLS / TILE)     // 6272, exact
#define NBLOCKS 1024               // 4 blocks/CU * 256 CUs
#define NCH     30
#define NTR     6
#define LCOORD  5.0f
#define LNOOBJ  0.5f
#define F4_YP   (TILE * NCH / 4)   // 960 float4 of y_pred per tile
#define F4_TILE (F4_YP + TILE * NTR / 4)   // 1152 float4 total per tile
#define LPT     (F4_TILE / TILE)   // 9 loads per thread, exact

__device__ __forceinline__ float iou_one(float x, float y, float w, float h,
                                         float t0, float t1, float t2, float t3) {
    float b1x1 = x - w * 0.5f, b1x2 = x + w * 0.5f;
    float b1y1 = y - h * 0.5f, b1y2 = y + h * 0.5f;
    float b2x1 = t0 - t2 * 0.5f, b2x2 = t0 + t2 * 0.5f;
    float b2y1 = t1 - t3 * 0.5f, b2y2 = t1 + t3 * 0.5f;
    float iw = fmaxf(fminf(b1x2, b2x2) - fmaxf(b1x1, b2x1), 0.0f);
    float ih = fmaxf(fminf(b1y2, b2y2) - fmaxf(b1y1, b2y1), 0.0f);
    float inter = iw * ih;
    float uni = w * h + t2 * t3 - inter;
    return inter / (uni + 1e-6f);
}

// Stage one 128-cell tile (yp then yt, contiguous) into LDS at dst[0..1151].
// 9 global_load_lds per thread; (s,wave) -> src array is wave-uniform, and
// dst index j = s*128+tid is linear in lane (required layout).
__device__ __forceinline__ void stage_tile(const float* __restrict__ yp,
                                           const float* __restrict__ yt,
                                           int tile, int tid, float4* dst) {
    const float4* gp4 = (const float4*)(yp + (size_t)tile * TILE * NCH);
    const float4* gt4 = (const float4*)(yt + (size_t)tile * TILE * NTR);
    #pragma unroll
    for (int s = 0; s < LPT; ++s) {
        int j = s * TILE + tid;
        const float4* src = (j < F4_YP) ? (gp4 + j) : (gt4 + (j - F4_YP));
        __builtin_amdgcn_global_load_lds(
            (const __attribute__((address_space(1))) void*)src,
            (__attribute__((address_space(3))) void*)(dst + j), 16, 0, 0);
    }
}

__global__ __launch_bounds__(128) void yolo_main(const float* __restrict__ yp,
                                                 const float* __restrict__ yt,
                                                 float* __restrict__ ws) {
    __shared__ float4 buf[2][F4_TILE];   // 2 x 18 KiB = 36.9 KB
    __shared__ float red[2][8];

    const int tid  = threadIdx.x;
    const int wave = tid >> 6, lane = tid & 63;
    float v[6] = {0.f, 0.f, 0.f, 0.f, 0.f, 0.f};

    const int b = blockIdx.x;
    const int n = (b < (NTILES - 6 * NBLOCKS)) ? 7 : 6;   // first 128 blocks do 7

    // ---- prologue: fill both buffers (18 outstanding loads/wave) ----
    stage_tile(yp, yt, b, tid, &buf[0][0]);
    stage_tile(yp, yt, b + NBLOCKS, tid, &buf[1][0]);

    for (int k = 0; k < n; ++k) {
        // wait for THIS tile's 9 loads (leave next tile's 9 in flight);
        // then barrier so every wave's loads for this buffer have landed.
        if (k == n - 1) { asm volatile("s_waitcnt vmcnt(0)" ::: "memory"); }
        else            { asm volatile("s_waitcnt vmcnt(9)" ::: "memory"); }
        __builtin_amdgcn_s_barrier();

        // ---- per-cell compute (identical expression order since round 1) ----
        {
            const float* p = (const float*)&buf[k & 1][0] + tid * NCH;
            const float* t = (const float*)&buf[k & 1][F4_YP] + tid * NTR;
            float t0 = t[0], t1 = t[1], t2 = t[2], t3 = t[3], t4 = t[4];
            int lbl = (int)t[5];

            float iou0 = iou_one(p[0], p[1], p[2], p[3], t0, t1, t2, t3);
            float iou1 = iou_one(p[5], p[6], p[7], p[8], t0, t1, t2, t3);
            // jnp.argmax picks FIRST max on ties -> box1 wins only if strictly greater
            int base = (iou1 > iou0) ? 5 : 0;
            float tb0 = p[base + 0], tb1 = p[base + 1], tb2 = p[base + 2];
            float tb3 = p[base + 3], tb4 = p[base + 4];

            float obj = (t4 != 0.0f) ? 1.0f : 0.0f;
            float noobj = 1.0f - obj;

            float dx = tb0 - t0, dy = tb1 - t1;
            float a0 = obj * (dx * dx + dy * dy);

            float s2 = sqrtf(t2);              // reference uses y_true[...,2] for BOTH size terms
            float d2 = sqrtf(tb2) - s2;
            float d3 = sqrtf(tb3) - s2;
            float a1 = obj * (d2 * d2 + d3 * d3);

            float pc = fminf(fmaxf(tb4, 1e-7f), 1.0f - 1e-7f);
            float bce = -(t4 * logf(pc) + (1.0f - t4) * log1pf(-pc));
            float a2 = obj * bce;
            float a3 = noobj * bce;

            float m = p[10];
            #pragma unroll
            for (int c = 11; c < 30; ++c) m = fmaxf(m, p[c]);
            float se = 0.0f;
            #pragma unroll
            for (int c = 10; c < 30; ++c) se += expf(p[c] - m);
            float nll = logf(se) + m - p[10 + lbl];
            float a4 = obj * nll;

            v[0] += a0; v[1] += a1; v[2] += a2; v[3] += a3; v[4] += a4; v[5] += obj;
        }

        // refill the buffer we just read with tile k+2 (stays in flight
        // across the next iteration's compute)
        if (k + 2 < n) {
            asm volatile("s_waitcnt lgkmcnt(0)" ::: "memory");  // my LDS reads done
            __builtin_amdgcn_s_barrier();                       // all waves done reading
            stage_tile(yp, yt, b + (k + 2) * NBLOCKS, tid, &buf[k & 1][0]);
        }
    }

    // ---- block reduce (2 waves) ----
    #pragma unroll
    for (int j = 0; j < 6; ++j) {
        #pragma unroll
        for (int off = 32; off > 0; off >>= 1)
            v[j] += __shfl_down(v[j], off, 64);
    }
    if (lane == 0) {
        #pragma unroll
        for (int j = 0; j < 6; ++j) red[wave][j] = v[j];
    }
    __syncthreads();   // safe here: no prefetch in flight (last iter drained)
    if (tid == 0) {
        float* dst = ws + (size_t)b * 8;
        #pragma unroll
        for (int j = 0; j < 6; ++j)
            dst[j] = red[0][j] + red[1][j];
    }
}

__global__ __launch_bounds__(256) void yolo_final(const float* __restrict__ ws,
                                                  float* __restrict__ out) {
    __shared__ float red[4][8];
    const int tid = threadIdx.x;
    float v[6] = {0.f, 0.f, 0.f, 0.f, 0.f, 0.f};
    for (int i = tid; i < NBLOCKS; i += 256) {
        const float* src = ws + (size_t)i * 8;
        #pragma unroll
        for (int j = 0; j < 6; ++j) v[j] += src[j];
    }
    #pragma unroll
    for (int j = 0; j < 6; ++j) {
        #pragma unroll
        for (int off = 32; off > 0; off >>= 1)
            v[j] += __shfl_down(v[j], off, 64);
    }
    const int wave = tid >> 6, lane = tid & 63;
    if (lane == 0) {
        #pragma unroll
        for (int j = 0; j < 6; ++j) red[wave][j] = v[j];
    }
    __syncthreads();
    if (tid == 0) {
        float a[6];
        #pragma unroll
        for (int j = 0; j < 6; ++j)
            a[j] = red[0][j] + red[1][j] + red[2][j] + red[3][j];
        float n_obj = a[5];
        float n_noobj = (float)CELLS - n_obj;
        out[0] = (LCOORD * (a[0] + a[1]) + a[2] + a[4]) / n_obj
               + LNOOBJ * a[3] / n_noobj;
    }
}

extern "C" void kernel_launch(void* const* d_in, const int* in_sizes, int n_in,
                              void* d_out, int out_size, void* d_ws, size_t ws_size,
                              hipStream_t stream) {
    const float* yp = (const float*)d_in[0];  // (16384,7,7,30)
    const float* yt = (const float*)d_in[1];  // (16384,7,7,6)
    float* out = (float*)d_out;
    float* ws = (float*)d_ws;   // needs 1024*8*4 = 32 KB

    yolo_main<<<NBLOCKS, TILE, 0, stream>>>(yp, yt, ws);
    yolo_final<<<1, 256, 0, stream>>>(ws, out);
}